// Round 2
// baseline (6035.703 us; speedup 1.0000x reference)
//
#include <hip/hip_runtime.h>

#define B_ 128
#define T_ 2048
#define H_ 128
#define G_ 512   // 4*H
#define IN_ 6

typedef _Float16 half2_t __attribute__((ext_vector_type(2)));
typedef _Float16 f16x8  __attribute__((ext_vector_type(8)));
typedef float    f32x4  __attribute__((ext_vector_type(4)));

#if defined(__has_builtin)
# if __has_builtin(__builtin_amdgcn_fdot2)
#  define HAVE_FDOT2 1
# endif
#endif

__device__ __forceinline__ unsigned short f2h_u(float f) {
  union { _Float16 h; unsigned short u; } v; v.h = (_Float16)f; return v.u;
}
__device__ __forceinline__ unsigned int pack2(float a, float b) {
  return (unsigned int)f2h_u(a) | ((unsigned int)f2h_u(b) << 16);
}
__device__ __forceinline__ half2_t u2h2(unsigned int u) {
  union { unsigned int u; half2_t h; } v; v.u = u; return v.h;
}
__device__ __forceinline__ float dot2_acc(unsigned int wpk, unsigned int hpk, float acc) {
#if HAVE_FDOT2
  return __builtin_amdgcn_fdot2(u2h2(wpk), u2h2(hpk), acc, false);
#else
  union { unsigned int u; half2_t h; } a, b; a.u = wpk; b.u = hpk;
  return acc + (float)a.h[0] * (float)b.h[0] + (float)a.h[1] * (float)b.h[1];
#endif
}
__device__ __forceinline__ float sigmoidf_(float x) { return 1.0f / (1.0f + __expf(-x)); }
__device__ __forceinline__ float tanhf_(float x) {
  x = fminf(fmaxf(x, -15.f), 15.f);
  float e = __expf(2.f * x);
  return (e - 1.f) / (e + 1.f);
}

// ---------------------------------------------------------------------------
// Layer-0 input contribution: xg[m,g] = (b_ih+b_hh)[g] + sum_i x[b,t0+tc,i]*Wih0[g,i]
// m = b*C + tc, chunk-local.
// ---------------------------------------------------------------------------
__global__ __launch_bounds__(256, 4)
void xg0_kernel(const float* __restrict__ x,     // fp32 [B][T][6]
                const float* __restrict__ Wih,   // fp32 [512][6]
                const float* __restrict__ bih,   // fp32 [512]
                const float* __restrict__ bhh,   // fp32 [512]
                float* __restrict__ xg, int C, int t0)
{
  int idx = blockIdx.x * 256 + threadIdx.x;  // over B*C*512
  int g = idx & (G_ - 1);
  int m = idx >> 9;
  int b = m / C, tc = m - b * C;
  const float* xr = x + ((size_t)b * T_ + (t0 + tc)) * IN_;
  const float* wr = Wih + g * IN_;
  float s = bih[g] + bhh[g];
#pragma unroll
  for (int i = 0; i < IN_; ++i) s += xr[i] * wr[i];
  xg[idx] = s;
}

// ---------------------------------------------------------------------------
// Layers 1/2 input GEMM: xg[m,n] = bias[n] + sum_k hin[m,k]*Wih[n,k]
// hin: f16 chunk-local [B*C][128]; Wih fp32 [512][128] converted to f16 in staging.
// Block tile 64(M) x 128(N); f16 MFMA 16x16x32.
// ---------------------------------------------------------------------------
__global__ __launch_bounds__(256, 2)
void gemm_xg(const unsigned short* __restrict__ hin,  // f16 [B*C][128]
             const float* __restrict__ Wih,           // fp32 [512][128]
             const float* __restrict__ bih,
             const float* __restrict__ bhh,
             float* __restrict__ xg)                  // fp32 [B*C][512]
{
  const int tid  = threadIdx.x;
  const int lane = tid & 63;
  const int wave = tid >> 6;
  const int m0 = blockIdx.x * 64;
  const int n0 = blockIdx.y * 128;

  __shared__ unsigned short Al[64 * 136];   // [m][k] f16, row stride 136 (272B, 16B-mult)
  __shared__ unsigned short Bl[128 * 136];  // [n][k] f16

  // stage A: 64 rows of hin (already f16) -- 4 threads/row, 32 elems each
  {
    int row = tid >> 2, q = tid & 3;
    const uint4* src = (const uint4*)(hin + (size_t)(m0 + row) * H_ + q * 32);
    uint4* dst = (uint4*)(Al + row * 136 + q * 32);
#pragma unroll
    for (int i = 0; i < 4; ++i) dst[i] = src[i];
  }
  // stage B: 128 rows of Wih (fp32 -> f16) -- 2 threads/row, 64 elems each
  {
    int row = tid >> 1, half = tid & 1;
    const float4* src = (const float4*)(Wih + (size_t)(n0 + row) * H_ + half * 64);
    uint4* dst = (uint4*)(Bl + row * 136 + half * 64);
#pragma unroll
    for (int i = 0; i < 8; ++i) {
      float4 a = src[2 * i], b = src[2 * i + 1];
      uint4 q;
      q.x = pack2(a.x, a.y); q.y = pack2(a.z, a.w);
      q.z = pack2(b.x, b.y); q.w = pack2(b.z, b.w);
      dst[i] = q;
    }
  }
  __syncthreads();

  const int wm = (wave >> 1) * 32;  // wave tile: 32(M) x 64(N)
  const int wn = (wave & 1) * 64;
  const int fr = lane & 15;
  const int fk = (lane >> 4) * 8;

  f32x4 acc[2][4];
#pragma unroll
  for (int i = 0; i < 2; ++i)
#pragma unroll
    for (int j = 0; j < 4; ++j) acc[i][j] = (f32x4){0.f, 0.f, 0.f, 0.f};

#pragma unroll
  for (int k0 = 0; k0 < 128; k0 += 32) {
    f16x8 af[2], bf[4];
#pragma unroll
    for (int i = 0; i < 2; ++i)
      af[i] = *(const f16x8*)(Al + (wm + i * 16 + fr) * 136 + k0 + fk);
#pragma unroll
    for (int j = 0; j < 4; ++j)
      bf[j] = *(const f16x8*)(Bl + (wn + j * 16 + fr) * 136 + k0 + fk);
#pragma unroll
    for (int i = 0; i < 2; ++i)
#pragma unroll
      for (int j = 0; j < 4; ++j)
        acc[i][j] = __builtin_amdgcn_mfma_f32_16x16x32_f16(af[i], bf[j], acc[i][j], 0, 0, 0);
  }

  // D layout: col(N)=lane&15, row(M)=(lane>>4)*4+reg
#pragma unroll
  for (int i = 0; i < 2; ++i) {
#pragma unroll
    for (int j = 0; j < 4; ++j) {
      int n = n0 + wn + j * 16 + fr;
      float bias = bih[n] + bhh[n];
#pragma unroll
      for (int r = 0; r < 4; ++r) {
        int mrow = m0 + wm + i * 16 + (lane >> 4) * 4 + r;
        xg[(size_t)mrow * G_ + n] = acc[i][j][r] + bias;
      }
    }
  }
}

// ---------------------------------------------------------------------------
// Recurrence scan: one workgroup per batch element, thread g owns gate row g.
// W_hh row packed f16x2 in 64 VGPRs; h broadcast via v_readlane + v_dot2_f32_f16.
// ---------------------------------------------------------------------------
__global__ __launch_bounds__(512, 2)
void lstm_scan(const float* __restrict__ xg,      // fp32 [B*C][512] chunk-local
               const float* __restrict__ Whh,     // fp32 [512][128]
               unsigned short* __restrict__ hout, // f16 [B*C][128] or null
               float* __restrict__ state_c,       // fp32 [B][128]
               unsigned int* __restrict__ state_h,// [B][64] packed f16x2
               int C, int first)
{
  const int tid  = threadIdx.x;
  const int b    = blockIdx.x;
  const int lane = tid & 63;

  __shared__ float gbuf[G_];
  __shared__ unsigned int hbuf[64];

  // load W_hh row (128 fp32) -> 64 packed f16 pairs in VGPRs
  unsigned int w[64];
  {
    const float4* wp = (const float4*)(Whh + (size_t)tid * H_);
#pragma unroll
    for (int i = 0; i < 32; ++i) {
      float4 q = wp[i];
      w[2 * i]     = pack2(q.x, q.y);
      w[2 * i + 1] = pack2(q.z, q.w);
    }
  }

  unsigned int hv = 0u;
  float c = 0.f;
  if (!first) {
    hv = state_h[b * 64 + lane];
    if (tid < H_) c = state_c[b * H_ + tid];
  }

  const float* xgb = xg + ((size_t)b * C) * G_ + tid;
  float cur = xgb[0];

  for (int t = 0; t < C; ++t) {
    int tn = (t + 1 < C) ? (t + 1) : t;
    float nxt = xgb[(size_t)tn * G_];  // prefetch for next iter

    float acc0 = cur, acc1 = 0.f;
    int hvi = (int)hv;
#pragma unroll
    for (int j = 0; j < 64; j += 2) {
      int s0 = __builtin_amdgcn_readlane(hvi, j);
      int s1 = __builtin_amdgcn_readlane(hvi, j + 1);
      acc0 = dot2_acc(w[j],     (unsigned int)s0, acc0);
      acc1 = dot2_acc(w[j + 1], (unsigned int)s1, acc1);
    }
    float pre = acc0 + acc1;
    // gate rows: [0,128)=i sig, [128,256)=f sig, [256,384)=g tanh, [384,512)=o sig
    float a = ((tid >> 7) == 2) ? tanhf_(pre) : sigmoidf_(pre);
    gbuf[tid] = a;
    __syncthreads();
    if (tid < H_) {
      float ai = gbuf[tid];
      float af = gbuf[tid + 128];
      float ag = gbuf[tid + 256];
      float ao = gbuf[tid + 384];
      c = af * c + ai * ag;
      float h = ao * tanhf_(c);
      unsigned short hb = f2h_u(h);
      ((unsigned short*)hbuf)[tid] = hb;
      if (hout) hout[((size_t)b * C + t) * H_ + tid] = hb;
    }
    __syncthreads();
    hv = hbuf[lane];
    cur = nxt;
  }

  if (tid < H_) state_c[b * H_ + tid] = c;
  if (tid < 64) state_h[b * 64 + tid] = hv;
}

// ---------------------------------------------------------------------------
// Head: out[b] = h_last[b,:] . W_out + b_out   (fp32 out)
// ---------------------------------------------------------------------------
__global__ void head_kernel(const unsigned int* __restrict__ state_h,  // [B][64] f16x2
                            const float* __restrict__ Wout,            // fp32 [128]
                            const float* __restrict__ bout,            // fp32 [1]
                            float* __restrict__ out)                   // fp32 [128]
{
  int b = threadIdx.x;  // 128 threads, 1 block
  float s = bout[0];
  for (int j = 0; j < 64; ++j) {
    unsigned int p = state_h[b * 64 + j];
    union { unsigned short u; _Float16 h; } lo, hi;
    lo.u = (unsigned short)(p & 0xffffu);
    hi.u = (unsigned short)(p >> 16);
    s += (float)lo.h * Wout[2 * j] + (float)hi.h * Wout[2 * j + 1];
  }
  out[b] = s;
}

// ---------------------------------------------------------------------------
extern "C" void kernel_launch(void* const* d_in, const int* in_sizes, int n_in,
                              void* d_out, int out_size, void* d_ws, size_t ws_size,
                              hipStream_t stream)
{
  const float* x = (const float*)d_in[0];
  const float* Wih[3] = {(const float*)d_in[1], (const float*)d_in[5], (const float*)d_in[9]};
  const float* Whh[3] = {(const float*)d_in[2], (const float*)d_in[6], (const float*)d_in[10]};
  const float* bih[3] = {(const float*)d_in[3], (const float*)d_in[7], (const float*)d_in[11]};
  const float* bhh[3] = {(const float*)d_in[4], (const float*)d_in[8], (const float*)d_in[12]};
  const float* Wout = (const float*)d_in[13];
  const float* bout = (const float*)d_in[14];
  float* out = (float*)d_out;

  // ---- workspace layout (chunk-pipelined; fits small ws_size) ----
  char* ws = (char*)d_ws;
  size_t off = 0;
  float* state_c0 = (float*)(ws + off); off += (size_t)B_ * H_ * 4;
  float* state_c1 = (float*)(ws + off); off += (size_t)B_ * H_ * 4;
  float* state_c2 = (float*)(ws + off); off += (size_t)B_ * H_ * 4;
  unsigned int* state_h0 = (unsigned int*)(ws + off); off += (size_t)B_ * 64 * 4;
  unsigned int* state_h1 = (unsigned int*)(ws + off); off += (size_t)B_ * 64 * 4;
  unsigned int* state_h2 = (unsigned int*)(ws + off); off += (size_t)B_ * 64 * 4;

  // choose largest chunk C (divides T) whose buffers fit ws_size
  int C = 256;
  while (C > 8) {
    size_t need = off + (size_t)B_ * C * G_ * 4     // xg fp32
                      + 2 * (size_t)B_ * C * H_ * 2; // h0buf,h1buf f16
    if (need <= ws_size) break;
    C >>= 1;
  }
  float* xg = (float*)(ws + off);                     off += (size_t)B_ * C * G_ * 4;
  unsigned short* h0buf = (unsigned short*)(ws + off); off += (size_t)B_ * C * H_ * 2;
  unsigned short* h1buf = (unsigned short*)(ws + off);

  float* state_c[3] = {state_c0, state_c1, state_c2};
  unsigned int* state_h[3] = {state_h0, state_h1, state_h2};

  const int NC = T_ / C;
  dim3 ggrid((B_ * C) / 64, G_ / 128);
  for (int k = 0; k < NC; ++k) {
    int t0 = k * C;
    int first = (k == 0) ? 1 : 0;
    // layer 0
    xg0_kernel<<<(B_ * C * G_) / 256, 256, 0, stream>>>(x, Wih[0], bih[0], bhh[0], xg, C, t0);
    lstm_scan<<<B_, 512, 0, stream>>>(xg, Whh[0], h0buf, state_c[0], state_h[0], C, first);
    // layer 1
    gemm_xg<<<ggrid, 256, 0, stream>>>(h0buf, Wih[1], bih[1], bhh[1], xg);
    lstm_scan<<<B_, 512, 0, stream>>>(xg, Whh[1], h1buf, state_c[1], state_h[1], C, first);
    // layer 2
    gemm_xg<<<ggrid, 256, 0, stream>>>(h1buf, Wih[2], bih[2], bhh[2], xg);
    lstm_scan<<<B_, 512, 0, stream>>>(xg, Whh[2], (unsigned short*)nullptr,
                                      state_c[2], state_h[2], C, first);
  }
  head_kernel<<<1, 128, 0, stream>>>(state_h[2], Wout, bout, out);
}

// Round 3
// 5891.435 us; speedup vs baseline: 1.0245x; 1.0245x over previous
//
#include <hip/hip_runtime.h>

#define B_ 128
#define T_ 2048
#define H_ 128
#define G_ 512   // 4*H
#define IN_ 6

typedef _Float16 half2_t __attribute__((ext_vector_type(2)));
typedef _Float16 f16x8  __attribute__((ext_vector_type(8)));
typedef float    f32x4  __attribute__((ext_vector_type(4)));

#if defined(__has_builtin)
# if __has_builtin(__builtin_amdgcn_fdot2)
#  define HAVE_FDOT2 1
# endif
#endif

__device__ __forceinline__ unsigned short f2h_u(float f) {
  union { _Float16 h; unsigned short u; } v; v.h = (_Float16)f; return v.u;
}
__device__ __forceinline__ unsigned int pack2(float a, float b) {
  return (unsigned int)f2h_u(a) | ((unsigned int)f2h_u(b) << 16);
}
__device__ __forceinline__ half2_t u2h2(unsigned int u) {
  union { unsigned int u; half2_t h; } v; v.u = u; return v.h;
}
__device__ __forceinline__ float dot2_acc(unsigned int wpk, unsigned int hpk, float acc) {
#if HAVE_FDOT2
  return __builtin_amdgcn_fdot2(u2h2(wpk), u2h2(hpk), acc, false);
#else
  union { unsigned int u; half2_t h; } a, b; a.u = wpk; b.u = hpk;
  return acc + (float)a.h[0] * (float)b.h[0] + (float)a.h[1] * (float)b.h[1];
#endif
}

// Permutation: scan-thread p <-> true gate row n.
//   p = w*64 + q*16 + i   where n = q*128 + u, u = w*16 + i
__device__ __forceinline__ int row_from_p(int p) {
  return ((p >> 4) & 3) * 128 + (p >> 6) * 16 + (p & 15);
}
__device__ __forceinline__ int p_from_row(int n) {
  return ((n >> 4) & 7) * 64 + (n >> 7) * 16 + (n & 15);
}

// ---------------------------------------------------------------------------
// Layer-0 input contribution (permuted columns):
// xg[m*512 + p] = bias[n(p)] + sum_i x[b,t0+tc,i]*Wih0[n(p),i]
// ---------------------------------------------------------------------------
__global__ __launch_bounds__(256, 4)
void xg0_kernel(const float* __restrict__ x,     // fp32 [B][T][6]
                const float* __restrict__ Wih,   // fp32 [512][6]
                const float* __restrict__ bih,   // fp32 [512]
                const float* __restrict__ bhh,   // fp32 [512]
                float* __restrict__ xg, int C, int t0)
{
  int idx = blockIdx.x * 256 + threadIdx.x;  // over B*C*512
  int p = idx & (G_ - 1);
  int g = row_from_p(p);
  int m = idx >> 9;
  int b = m / C, tc = m - b * C;
  const float* xr = x + ((size_t)b * T_ + (t0 + tc)) * IN_;
  const float* wr = Wih + g * IN_;
  float s = bih[g] + bhh[g];
#pragma unroll
  for (int i = 0; i < IN_; ++i) s += xr[i] * wr[i];
  xg[idx] = s;
}

// ---------------------------------------------------------------------------
// Layers 1/2 input GEMM (permuted output columns):
// xg[m*512 + p(n)] = bias[n] + sum_k hin[m,k]*Wih[n,k]
// ---------------------------------------------------------------------------
__global__ __launch_bounds__(256, 2)
void gemm_xg(const unsigned short* __restrict__ hin,  // f16 [B*C][128]
             const float* __restrict__ Wih,           // fp32 [512][128]
             const float* __restrict__ bih,
             const float* __restrict__ bhh,
             float* __restrict__ xg)                  // fp32 [B*C][512] permuted
{
  const int tid  = threadIdx.x;
  const int lane = tid & 63;
  const int wave = tid >> 6;
  const int m0 = blockIdx.x * 64;
  const int n0 = blockIdx.y * 128;

  __shared__ unsigned short Al[64 * 136];   // [m][k] f16
  __shared__ unsigned short Bl[128 * 136];  // [n][k] f16

  {
    int row = tid >> 2, qq = tid & 3;
    const uint4* src = (const uint4*)(hin + (size_t)(m0 + row) * H_ + qq * 32);
    uint4* dst = (uint4*)(Al + row * 136 + qq * 32);
#pragma unroll
    for (int i = 0; i < 4; ++i) dst[i] = src[i];
  }
  {
    int row = tid >> 1, half = tid & 1;
    const float4* src = (const float4*)(Wih + (size_t)(n0 + row) * H_ + half * 64);
    uint4* dst = (uint4*)(Bl + row * 136 + half * 64);
#pragma unroll
    for (int i = 0; i < 8; ++i) {
      float4 a = src[2 * i], b = src[2 * i + 1];
      uint4 q;
      q.x = pack2(a.x, a.y); q.y = pack2(a.z, a.w);
      q.z = pack2(b.x, b.y); q.w = pack2(b.z, b.w);
      dst[i] = q;
    }
  }
  __syncthreads();

  const int wm = (wave >> 1) * 32;  // wave tile: 32(M) x 64(N)
  const int wn = (wave & 1) * 64;
  const int fr = lane & 15;
  const int fk = (lane >> 4) * 8;

  f32x4 acc[2][4];
#pragma unroll
  for (int i = 0; i < 2; ++i)
#pragma unroll
    for (int j = 0; j < 4; ++j) acc[i][j] = (f32x4){0.f, 0.f, 0.f, 0.f};

#pragma unroll
  for (int k0 = 0; k0 < 128; k0 += 32) {
    f16x8 af[2], bf[4];
#pragma unroll
    for (int i = 0; i < 2; ++i)
      af[i] = *(const f16x8*)(Al + (wm + i * 16 + fr) * 136 + k0 + fk);
#pragma unroll
    for (int j = 0; j < 4; ++j)
      bf[j] = *(const f16x8*)(Bl + (wn + j * 16 + fr) * 136 + k0 + fk);
#pragma unroll
    for (int i = 0; i < 2; ++i)
#pragma unroll
      for (int j = 0; j < 4; ++j)
        acc[i][j] = __builtin_amdgcn_mfma_f32_16x16x32_f16(af[i], bf[j], acc[i][j], 0, 0, 0);
  }

#pragma unroll
  for (int i = 0; i < 2; ++i) {
#pragma unroll
    for (int j = 0; j < 4; ++j) {
      int n = n0 + wn + j * 16 + fr;
      int pcol = p_from_row(n);
      float bias = bih[n] + bhh[n];
#pragma unroll
      for (int r = 0; r < 4; ++r) {
        int mrow = m0 + wm + i * 16 + (lane >> 4) * 4 + r;
        xg[(size_t)mrow * G_ + pcol] = acc[i][j][r] + bias;
      }
    }
  }
}

// ---------------------------------------------------------------------------
// Recurrence scan, 1 barrier/step.
// Thread p = wave w (0..7), lane l: gate q = l>>4, unit u = 16w + (l&15).
// Gate combine via 4 in-wave shuffles; c,h replicated across the 4 q-lanes.
// h ping-pong through 256B of LDS; hv (packed f16x2) broadcast via readlane.
// ---------------------------------------------------------------------------
__global__ __launch_bounds__(512, 2)
void lstm_scan(const float* __restrict__ xg,      // fp32 [B*C][512] permuted cols
               const float* __restrict__ Whh,     // fp32 [512][128]
               unsigned short* __restrict__ hout, // f16 [B*C][128] or null
               float* __restrict__ state_c,       // fp32 [B][128]
               unsigned int* __restrict__ state_h,// [B][64] packed f16x2
               int C, int first)
{
  const int tid  = threadIdx.x;
  const int b    = blockIdx.x;
  const int lane = tid & 63;
  const int wv   = tid >> 6;
  const int i16  = lane & 15;
  const int q    = lane >> 4;
  const int u    = wv * 16 + i16;        // hidden unit owned (for combine)
  const int row  = q * 128 + u;          // true gate row for the dot product
  const bool qz  = (q == 0);

  __shared__ unsigned int hbuf[2][64];

  // W_hh row -> 64 packed f16 pairs in VGPRs
  unsigned int w[64];
  {
    const float4* wp = (const float4*)(Whh + (size_t)row * H_);
#pragma unroll
    for (int k = 0; k < 32; ++k) {
      float4 f = wp[k];
      w[2 * k]     = pack2(f.x, f.y);
      w[2 * k + 1] = pack2(f.z, f.w);
    }
  }

  float c = 0.f;
  unsigned int hv = 0u;
  if (!first) {
    c  = state_c[b * H_ + u];
    hv = state_h[b * 64 + lane];
  }

  const float* xgp = xg + (size_t)b * C * G_ + tid;
  float cur = xgp[0];
  float nxt = xgp[(C > 1) ? G_ : 0];

  const float zs = (q == 2) ? -2.f : -1.f;   // tanh vs sigmoid exponent scale
  const bool isg = (q == 2);

  for (int t = 0; t < C; ++t) {
    int tp = (t + 2 < C) ? (t + 2) : t;
    float pf = xgp[(size_t)tp * G_];         // prefetch t+2

    // pre-activation: xg + W_hh[row,:] . h
    float a0 = cur, a1 = 0.f, a2 = 0.f, a3 = 0.f;
    int hvi = (int)hv;
#pragma unroll
    for (int j = 0; j < 64; j += 4) {
      int s0 = __builtin_amdgcn_readlane(hvi, j);
      int s1 = __builtin_amdgcn_readlane(hvi, j + 1);
      int s2 = __builtin_amdgcn_readlane(hvi, j + 2);
      int s3 = __builtin_amdgcn_readlane(hvi, j + 3);
      a0 = dot2_acc(w[j],     (unsigned int)s0, a0);
      a1 = dot2_acc(w[j + 1], (unsigned int)s1, a1);
      a2 = dot2_acc(w[j + 2], (unsigned int)s2, a2);
      a3 = dot2_acc(w[j + 3], (unsigned int)s3, a3);
    }
    float pre = (a0 + a1) + (a2 + a3);

    // unified activation: sigmoid(x)=1/(1+e^-x); tanh(x)=2/(1+e^-2x)-1
    float y = __expf(zs * pre);
    float r = 1.0f / (1.0f + y);
    float a = isg ? (2.0f * r - 1.0f) : r;

    // gather the 4 gates of unit u (all in this wave)
    float gi = __shfl(a, i16,      64);
    float gf = __shfl(a, 16 + i16, 64);
    float gg = __shfl(a, 32 + i16, 64);
    float go = __shfl(a, 48 + i16, 64);

    c = gf * c + gi * gg;                       // identical in all 4 q-lanes
    float th = 2.0f / (1.0f + __expf(-2.0f * c)) - 1.0f;
    float h = go * th;
    unsigned short hb = f2h_u(h);

    if (qz) {
      ((unsigned short*)hbuf[t & 1])[u] = hb;
      if (hout) hout[((size_t)b * C + t) * H_ + u] = hb;
    }
    __syncthreads();                             // single barrier (ping-pong)
    hv = hbuf[t & 1][lane];
    cur = nxt;
    nxt = pf;
  }

  if (qz) state_c[b * H_ + u] = c;
  if (wv == 0) state_h[b * 64 + lane] = hv;
}

// ---------------------------------------------------------------------------
// Head: out[b] = h_last[b,:] . W_out + b_out   (fp32 out)
// ---------------------------------------------------------------------------
__global__ void head_kernel(const unsigned int* __restrict__ state_h,  // [B][64] f16x2
                            const float* __restrict__ Wout,            // fp32 [128]
                            const float* __restrict__ bout,            // fp32 [1]
                            float* __restrict__ out)                   // fp32 [128]
{
  int b = threadIdx.x;  // 128 threads, 1 block
  float s = bout[0];
  for (int j = 0; j < 64; ++j) {
    unsigned int p = state_h[b * 64 + j];
    union { unsigned short u; _Float16 h; } lo, hi;
    lo.u = (unsigned short)(p & 0xffffu);
    hi.u = (unsigned short)(p >> 16);
    s += (float)lo.h * Wout[2 * j] + (float)hi.h * Wout[2 * j + 1];
  }
  out[b] = s;
}

// ---------------------------------------------------------------------------
extern "C" void kernel_launch(void* const* d_in, const int* in_sizes, int n_in,
                              void* d_out, int out_size, void* d_ws, size_t ws_size,
                              hipStream_t stream)
{
  const float* x = (const float*)d_in[0];
  const float* Wih[3] = {(const float*)d_in[1], (const float*)d_in[5], (const float*)d_in[9]};
  const float* Whh[3] = {(const float*)d_in[2], (const float*)d_in[6], (const float*)d_in[10]};
  const float* bih[3] = {(const float*)d_in[3], (const float*)d_in[7], (const float*)d_in[11]};
  const float* bhh[3] = {(const float*)d_in[4], (const float*)d_in[8], (const float*)d_in[12]};
  const float* Wout = (const float*)d_in[13];
  const float* bout = (const float*)d_in[14];
  float* out = (float*)d_out;

  char* ws = (char*)d_ws;
  size_t off = 0;
  float* state_c0 = (float*)(ws + off); off += (size_t)B_ * H_ * 4;
  float* state_c1 = (float*)(ws + off); off += (size_t)B_ * H_ * 4;
  float* state_c2 = (float*)(ws + off); off += (size_t)B_ * H_ * 4;
  unsigned int* state_h0 = (unsigned int*)(ws + off); off += (size_t)B_ * 64 * 4;
  unsigned int* state_h1 = (unsigned int*)(ws + off); off += (size_t)B_ * 64 * 4;
  unsigned int* state_h2 = (unsigned int*)(ws + off); off += (size_t)B_ * 64 * 4;

  int C = 256;
  while (C > 8) {
    size_t need = off + (size_t)B_ * C * G_ * 4
                      + 2 * (size_t)B_ * C * H_ * 2;
    if (need <= ws_size) break;
    C >>= 1;
  }
  float* xg = (float*)(ws + off);                      off += (size_t)B_ * C * G_ * 4;
  unsigned short* h0buf = (unsigned short*)(ws + off); off += (size_t)B_ * C * H_ * 2;
  unsigned short* h1buf = (unsigned short*)(ws + off);

  float* state_c[3] = {state_c0, state_c1, state_c2};
  unsigned int* state_h[3] = {state_h0, state_h1, state_h2};

  const int NC = T_ / C;
  dim3 ggrid((B_ * C) / 64, G_ / 128);
  for (int k = 0; k < NC; ++k) {
    int t0 = k * C;
    int first = (k == 0) ? 1 : 0;
    xg0_kernel<<<(B_ * C * G_) / 256, 256, 0, stream>>>(x, Wih[0], bih[0], bhh[0], xg, C, t0);
    lstm_scan<<<B_, 512, 0, stream>>>(xg, Whh[0], h0buf, state_c[0], state_h[0], C, first);
    gemm_xg<<<ggrid, 256, 0, stream>>>(h0buf, Wih[1], bih[1], bhh[1], xg);
    lstm_scan<<<B_, 512, 0, stream>>>(xg, Whh[1], h1buf, state_c[1], state_h[1], C, first);
    gemm_xg<<<ggrid, 256, 0, stream>>>(h1buf, Wih[2], bih[2], bhh[2], xg);
    lstm_scan<<<B_, 512, 0, stream>>>(xg, Whh[2], (unsigned short*)nullptr,
                                      state_c[2], state_h[2], C, first);
  }
  head_kernel<<<1, 128, 0, stream>>>(state_h[2], Wout, bout, out);
}

// Round 4
// 5848.737 us; speedup vs baseline: 1.0320x; 1.0073x over previous
//
#include <hip/hip_runtime.h>

#define B_ 128
#define T_ 2048
#define H_ 128
#define G_ 512   // 4*H
#define IN_ 6
#define S_ 8     // scan step-group size (vmem drained once per group)

typedef _Float16 half2_t __attribute__((ext_vector_type(2)));
typedef _Float16 f16x8  __attribute__((ext_vector_type(8)));
typedef float    f32x4  __attribute__((ext_vector_type(4)));

#if defined(__has_builtin)
# if __has_builtin(__builtin_amdgcn_fdot2)
#  define HAVE_FDOT2 1
# endif
#endif

__device__ __forceinline__ unsigned short f2h_u(float f) {
  union { _Float16 h; unsigned short u; } v; v.h = (_Float16)f; return v.u;
}
__device__ __forceinline__ unsigned int pack2(float a, float b) {
  return (unsigned int)f2h_u(a) | ((unsigned int)f2h_u(b) << 16);
}
__device__ __forceinline__ half2_t u2h2(unsigned int u) {
  union { unsigned int u; half2_t h; } v; v.u = u; return v.h;
}
__device__ __forceinline__ float dot2_acc(unsigned int wpk, unsigned int hpk, float acc) {
#if HAVE_FDOT2
  return __builtin_amdgcn_fdot2(u2h2(wpk), u2h2(hpk), acc, false);
#else
  union { unsigned int u; half2_t h; } a, b; a.u = wpk; b.u = hpk;
  return acc + (float)a.h[0] * (float)b.h[0] + (float)a.h[1] * (float)b.h[1];
#endif
}

// Permutation: scan-thread p <-> true gate row n.
//   p = w*64 + q*16 + i   where n = q*128 + u, u = w*16 + i
__device__ __forceinline__ int row_from_p(int p) {
  return ((p >> 4) & 3) * 128 + (p >> 6) * 16 + (p & 15);
}
__device__ __forceinline__ int p_from_row(int n) {
  return ((n >> 4) & 7) * 64 + (n >> 7) * 16 + (n & 15);
}

// ---------------------------------------------------------------------------
// Layer-0 input contribution (permuted columns):
// xg[m*512 + p] = bias[n(p)] + sum_i x[b,t0+tc,i]*Wih0[n(p),i]
// ---------------------------------------------------------------------------
__global__ __launch_bounds__(256, 4)
void xg0_kernel(const float* __restrict__ x,     // fp32 [B][T][6]
                const float* __restrict__ Wih,   // fp32 [512][6]
                const float* __restrict__ bih,   // fp32 [512]
                const float* __restrict__ bhh,   // fp32 [512]
                float* __restrict__ xg, int C, int t0)
{
  int idx = blockIdx.x * 256 + threadIdx.x;  // over B*C*512
  int p = idx & (G_ - 1);
  int g = row_from_p(p);
  int m = idx >> 9;
  int b = m / C, tc = m - b * C;
  const float* xr = x + ((size_t)b * T_ + (t0 + tc)) * IN_;
  const float* wr = Wih + g * IN_;
  float s = bih[g] + bhh[g];
#pragma unroll
  for (int i = 0; i < IN_; ++i) s += xr[i] * wr[i];
  xg[idx] = s;
}

// ---------------------------------------------------------------------------
// Layers 1/2 input GEMM (permuted output columns):
// xg[m*512 + p(n)] = bias[n] + sum_k hin[m,k]*Wih[n,k]
// ---------------------------------------------------------------------------
__global__ __launch_bounds__(256, 2)
void gemm_xg(const unsigned short* __restrict__ hin,  // f16 [B*C][128]
             const float* __restrict__ Wih,           // fp32 [512][128]
             const float* __restrict__ bih,
             const float* __restrict__ bhh,
             float* __restrict__ xg)                  // fp32 [B*C][512] permuted
{
  const int tid  = threadIdx.x;
  const int lane = tid & 63;
  const int wave = tid >> 6;
  const int m0 = blockIdx.x * 64;
  const int n0 = blockIdx.y * 128;

  __shared__ unsigned short Al[64 * 136];   // [m][k] f16
  __shared__ unsigned short Bl[128 * 136];  // [n][k] f16

  {
    int row = tid >> 2, qq = tid & 3;
    const uint4* src = (const uint4*)(hin + (size_t)(m0 + row) * H_ + qq * 32);
    uint4* dst = (uint4*)(Al + row * 136 + qq * 32);
#pragma unroll
    for (int i = 0; i < 4; ++i) dst[i] = src[i];
  }
  {
    int row = tid >> 1, half = tid & 1;
    const float4* src = (const float4*)(Wih + (size_t)(n0 + row) * H_ + half * 64);
    uint4* dst = (uint4*)(Bl + row * 136 + half * 64);
#pragma unroll
    for (int i = 0; i < 8; ++i) {
      float4 a = src[2 * i], b = src[2 * i + 1];
      uint4 q;
      q.x = pack2(a.x, a.y); q.y = pack2(a.z, a.w);
      q.z = pack2(b.x, b.y); q.w = pack2(b.z, b.w);
      dst[i] = q;
    }
  }
  __syncthreads();

  const int wm = (wave >> 1) * 32;  // wave tile: 32(M) x 64(N)
  const int wn = (wave & 1) * 64;
  const int fr = lane & 15;
  const int fk = (lane >> 4) * 8;

  f32x4 acc[2][4];
#pragma unroll
  for (int i = 0; i < 2; ++i)
#pragma unroll
    for (int j = 0; j < 4; ++j) acc[i][j] = (f32x4){0.f, 0.f, 0.f, 0.f};

#pragma unroll
  for (int k0 = 0; k0 < 128; k0 += 32) {
    f16x8 af[2], bf[4];
#pragma unroll
    for (int i = 0; i < 2; ++i)
      af[i] = *(const f16x8*)(Al + (wm + i * 16 + fr) * 136 + k0 + fk);
#pragma unroll
    for (int j = 0; j < 4; ++j)
      bf[j] = *(const f16x8*)(Bl + (wn + j * 16 + fr) * 136 + k0 + fk);
#pragma unroll
    for (int i = 0; i < 2; ++i)
#pragma unroll
      for (int j = 0; j < 4; ++j)
        acc[i][j] = __builtin_amdgcn_mfma_f32_16x16x32_f16(af[i], bf[j], acc[i][j], 0, 0, 0);
  }

#pragma unroll
  for (int i = 0; i < 2; ++i) {
#pragma unroll
    for (int j = 0; j < 4; ++j) {
      int n = n0 + wn + j * 16 + fr;
      int pcol = p_from_row(n);
      float bias = bih[n] + bhh[n];
#pragma unroll
      for (int r = 0; r < 4; ++r) {
        int mrow = m0 + wm + i * 16 + (lane >> 4) * 4 + r;
        xg[(size_t)mrow * G_ + pcol] = acc[i][j][r] + bias;
      }
    }
  }
}

// ---------------------------------------------------------------------------
// Recurrence scan, grouped S_=8: per group, prefetch next group's xg into
// registers and defer hout stores to group end, so the compiler's
// `s_waitcnt vmcnt(0)` before each per-step s_barrier has nothing in flight
// (drain cost paid once per group, not per step).
// Thread p = wave w (0..7), lane l: gate q = l>>4, unit u = 16w + (l&15).
// ---------------------------------------------------------------------------
__global__ __launch_bounds__(512, 2)
void lstm_scan(const float* __restrict__ xg,      // fp32 [B*C][512] permuted cols
               const float* __restrict__ Whh,     // fp32 [512][128]
               unsigned short* __restrict__ hout, // f16 [B*C][128] or null
               float* __restrict__ state_c,       // fp32 [B][128]
               unsigned int* __restrict__ state_h,// [B][64] packed f16x2
               int C, int first)
{
  const int tid  = threadIdx.x;
  const int b    = blockIdx.x;
  const int lane = tid & 63;
  const int wv   = tid >> 6;
  const int i16  = lane & 15;
  const int q    = lane >> 4;
  const int u    = wv * 16 + i16;        // hidden unit owned (for combine)
  const int row  = q * 128 + u;          // true gate row for the dot product
  const bool qz  = (q == 0);

  __shared__ unsigned int hbuf[2][64];

  // W_hh row -> 64 packed f16 pairs in VGPRs
  unsigned int w[64];
  {
    const float4* wp = (const float4*)(Whh + (size_t)row * H_);
#pragma unroll
    for (int k = 0; k < 32; ++k) {
      float4 f = wp[k];
      w[2 * k]     = pack2(f.x, f.y);
      w[2 * k + 1] = pack2(f.z, f.w);
    }
  }

  float c = 0.f;
  unsigned int hv = 0u;
  if (!first) {
    c  = state_c[b * H_ + u];
    hv = state_h[b * 64 + lane];
  }

  const float* xgp = xg + (size_t)b * C * G_ + tid;

  const float zs = (q == 2) ? -2.f : -1.f;   // tanh vs sigmoid exponent scale
  const bool isg = (q == 2);

  float xa[S_], xb[S_];
#pragma unroll
  for (int s = 0; s < S_; ++s) xa[s] = xgp[(size_t)s * G_];

  unsigned short hreg[S_];

  for (int g0 = 0; g0 < C; g0 += S_) {
    // prefetch next group's xg (single vmcnt drain at this group's 1st barrier)
    int gn = (g0 + S_ < C) ? (g0 + S_) : g0;
#pragma unroll
    for (int s = 0; s < S_; ++s) xb[s] = xgp[(size_t)(gn + s) * G_];

#pragma unroll
    for (int s = 0; s < S_; ++s) {
      // pre-activation: xg + W_hh[row,:] . h
      float a0 = xa[s], a1 = 0.f, a2 = 0.f, a3 = 0.f;
      int hvi = (int)hv;
#pragma unroll
      for (int j = 0; j < 64; j += 4) {
        int s0 = __builtin_amdgcn_readlane(hvi, j);
        int s1 = __builtin_amdgcn_readlane(hvi, j + 1);
        int s2 = __builtin_amdgcn_readlane(hvi, j + 2);
        int s3 = __builtin_amdgcn_readlane(hvi, j + 3);
        a0 = dot2_acc(w[j],     (unsigned int)s0, a0);
        a1 = dot2_acc(w[j + 1], (unsigned int)s1, a1);
        a2 = dot2_acc(w[j + 2], (unsigned int)s2, a2);
        a3 = dot2_acc(w[j + 3], (unsigned int)s3, a3);
      }
      float pre = (a0 + a1) + (a2 + a3);

      // unified activation: sigmoid(x)=1/(1+e^-x); tanh(x)=2/(1+e^-2x)-1
      float y = __expf(zs * pre);
      float r = 1.0f / (1.0f + y);
      float a = isg ? (2.0f * r - 1.0f) : r;

      // gather the 4 gates of unit u (all in this wave)
      float gi = __shfl(a, i16,      64);
      float gf = __shfl(a, 16 + i16, 64);
      float gg = __shfl(a, 32 + i16, 64);
      float go = __shfl(a, 48 + i16, 64);

      c = gf * c + gi * gg;                       // identical in all 4 q-lanes
      float th = 2.0f / (1.0f + __expf(-2.0f * c)) - 1.0f;
      float h = go * th;
      unsigned short hb = f2h_u(h);
      hreg[s] = hb;

      if (qz) ((unsigned short*)hbuf[s & 1])[u] = hb;
      __syncthreads();                             // vmcnt already drained
      hv = hbuf[s & 1][lane];
    }

    // deferred h-sequence stores (drained at next group's first barrier)
    if (hout && qz) {
#pragma unroll
      for (int s = 0; s < S_; ++s)
        hout[((size_t)b * C + (g0 + s)) * H_ + u] = hreg[s];
    }
#pragma unroll
    for (int s = 0; s < S_; ++s) xa[s] = xb[s];
  }

  if (qz) state_c[b * H_ + u] = c;
  if (wv == 0) state_h[b * 64 + lane] = hv;
}

// ---------------------------------------------------------------------------
// Head: out[b] = h_last[b,:] . W_out + b_out   (fp32 out)
// ---------------------------------------------------------------------------
__global__ void head_kernel(const unsigned int* __restrict__ state_h,  // [B][64] f16x2
                            const float* __restrict__ Wout,            // fp32 [128]
                            const float* __restrict__ bout,            // fp32 [1]
                            float* __restrict__ out)                   // fp32 [128]
{
  int b = threadIdx.x;  // 128 threads, 1 block
  float s = bout[0];
  for (int j = 0; j < 64; ++j) {
    unsigned int p = state_h[b * 64 + j];
    union { unsigned short u; _Float16 h; } lo, hi;
    lo.u = (unsigned short)(p & 0xffffu);
    hi.u = (unsigned short)(p >> 16);
    s += (float)lo.h * Wout[2 * j] + (float)hi.h * Wout[2 * j + 1];
  }
  out[b] = s;
}

// ---------------------------------------------------------------------------
extern "C" void kernel_launch(void* const* d_in, const int* in_sizes, int n_in,
                              void* d_out, int out_size, void* d_ws, size_t ws_size,
                              hipStream_t stream)
{
  const float* x = (const float*)d_in[0];
  const float* Wih[3] = {(const float*)d_in[1], (const float*)d_in[5], (const float*)d_in[9]};
  const float* Whh[3] = {(const float*)d_in[2], (const float*)d_in[6], (const float*)d_in[10]};
  const float* bih[3] = {(const float*)d_in[3], (const float*)d_in[7], (const float*)d_in[11]};
  const float* bhh[3] = {(const float*)d_in[4], (const float*)d_in[8], (const float*)d_in[12]};
  const float* Wout = (const float*)d_in[13];
  const float* bout = (const float*)d_in[14];
  float* out = (float*)d_out;

  char* ws = (char*)d_ws;
  size_t off = 0;
  float* state_c0 = (float*)(ws + off); off += (size_t)B_ * H_ * 4;
  float* state_c1 = (float*)(ws + off); off += (size_t)B_ * H_ * 4;
  float* state_c2 = (float*)(ws + off); off += (size_t)B_ * H_ * 4;
  unsigned int* state_h0 = (unsigned int*)(ws + off); off += (size_t)B_ * 64 * 4;
  unsigned int* state_h1 = (unsigned int*)(ws + off); off += (size_t)B_ * 64 * 4;
  unsigned int* state_h2 = (unsigned int*)(ws + off); off += (size_t)B_ * 64 * 4;

  int C = 256;
  while (C > 8) {
    size_t need = off + (size_t)B_ * C * G_ * 4
                      + 2 * (size_t)B_ * C * H_ * 2;
    if (need <= ws_size) break;
    C >>= 1;
  }
  float* xg = (float*)(ws + off);                      off += (size_t)B_ * C * G_ * 4;
  unsigned short* h0buf = (unsigned short*)(ws + off); off += (size_t)B_ * C * H_ * 2;
  unsigned short* h1buf = (unsigned short*)(ws + off);

  float* state_c[3] = {state_c0, state_c1, state_c2};
  unsigned int* state_h[3] = {state_h0, state_h1, state_h2};

  const int NC = T_ / C;
  dim3 ggrid((B_ * C) / 64, G_ / 128);
  for (int k = 0; k < NC; ++k) {
    int t0 = k * C;
    int first = (k == 0) ? 1 : 0;
    xg0_kernel<<<(B_ * C * G_) / 256, 256, 0, stream>>>(x, Wih[0], bih[0], bhh[0], xg, C, t0);
    lstm_scan<<<B_, 512, 0, stream>>>(xg, Whh[0], h0buf, state_c[0], state_h[0], C, first);
    gemm_xg<<<ggrid, 256, 0, stream>>>(h0buf, Wih[1], bih[1], bhh[1], xg);
    lstm_scan<<<B_, 512, 0, stream>>>(xg, Whh[1], h1buf, state_c[1], state_h[1], C, first);
    gemm_xg<<<ggrid, 256, 0, stream>>>(h1buf, Wih[2], bih[2], bhh[2], xg);
    lstm_scan<<<B_, 512, 0, stream>>>(xg, Whh[2], (unsigned short*)nullptr,
                                      state_c[2], state_h[2], C, first);
  }
  head_kernel<<<1, 128, 0, stream>>>(state_h[2], Wout, bout, out);
}

// Round 5
// 4711.355 us; speedup vs baseline: 1.2811x; 1.2414x over previous
//
#include <hip/hip_runtime.h>

#define B_ 128
#define T_ 2048
#define H_ 128
#define IN_ 6
#define GRP_ 8            // steps per inner group
#define NGRP_ (T_ / GRP_) // 256
#define CHUNK_ 32         // steps per flag chunk

typedef _Float16 f16x8 __attribute__((ext_vector_type(8)));
typedef float    f32x4 __attribute__((ext_vector_type(4)));

__device__ __forceinline__ unsigned short f2h_u(float f) {
  union { _Float16 h; unsigned short u; } v; v.h = (_Float16)f; return v.u;
}
__device__ __forceinline__ unsigned int pack2(float a, float b) {
  return (unsigned int)f2h_u(a) | ((unsigned int)f2h_u(b) << 16);
}
__device__ __forceinline__ float sigf_(float x) { return 1.0f / (1.0f + __expf(-x)); }
__device__ __forceinline__ float tanhf_(float x) {
  x = fminf(fmaxf(x, -15.f), 15.f);
  float e = __expf(2.f * x);
  return (e - 1.f) / (e + 1.f);
}
__device__ __forceinline__ f16x8 load_w8(const float* __restrict__ p) {
  f16x8 r;
#pragma unroll
  for (int i = 0; i < 8; ++i) r[i] = (_Float16)p[i];
  return r;
}

__global__ void init_flags(unsigned int* flags) {
  if (threadIdx.x < 16) flags[threadIdx.x] = 0u;
}

// ---------------------------------------------------------------------------
// Persistent pipelined 3-layer LSTM. 24 WGs: layer = bid>>3, batch-group = bid&7.
// Per WG: batches [16bg,16bg+16). Gates via MFMA 16x16x32 f16:
//   A = weight rows (M: gate rows), B = h rows [batch][k] (N: batch).
//   D: col = lane&15 = batch, row = quad*4+r = unit-within-16.
// Wave w owns units [16w,16w+16): all 4 gates of a unit land in ONE lane.
// h state ping-pongs through LDS (1 barrier/step). Layer handoff through a
// single in-place global f16 buffer + device-scope flags (32-step chunks).
// ---------------------------------------------------------------------------
__global__ __launch_bounds__(512, 2)
void lstm_pipe(const float* __restrict__ x,
               const float* __restrict__ Wih0, const float* __restrict__ Whh0,
               const float* __restrict__ bih0, const float* __restrict__ bhh0,
               const float* __restrict__ Wih1, const float* __restrict__ Whh1,
               const float* __restrict__ bih1, const float* __restrict__ bhh1,
               const float* __restrict__ Wih2, const float* __restrict__ Whh2,
               const float* __restrict__ bih2, const float* __restrict__ bhh2,
               unsigned short* __restrict__ region,   // f16 [B][T][128] (in-place l0h->l1h)
               unsigned int* __restrict__ state_h,    // [B][64] packed f16x2 (final l2 h)
               unsigned int* __restrict__ flags)      // [2][8]
{
  const int layer = blockIdx.x >> 3;
  const int bg    = blockIdx.x & 7;
  const int tid   = threadIdx.x;
  const int lane  = tid & 63;
  const int wv    = tid >> 6;       // 0..7: owns units [16wv,16wv+16)
  const int n16   = lane & 15;      // batch within group
  const int quad  = lane >> 4;

  const float* Wih = (layer == 0) ? Wih0 : ((layer == 1) ? Wih1 : Wih2);
  const float* Whh = (layer == 0) ? Whh0 : ((layer == 1) ? Whh1 : Whh2);
  const float* bih = (layer == 0) ? bih0 : ((layer == 1) ? bih1 : bih2);
  const float* bhh = (layer == 0) ? bhh0 : ((layer == 1) ? bhh1 : bhh2);

  __shared__ unsigned short hstate[2][16][136];       // ping-pong h [batch][unit]
  __shared__ unsigned short hbufL[GRP_][16][136];     // group h_in (layers 1,2)
  __shared__ unsigned short xbuf[GRP_][16][8];        // group x frag (layer 0)

  // ---- weights -> register A-frags (m = lane&15 = row-in-tile, k = quad*8+j)
  f16x8 whh[4][4];
#pragma unroll
  for (int j = 0; j < 4; ++j)
#pragma unroll
    for (int kc = 0; kc < 4; ++kc)
      whh[j][kc] = load_w8(Whh + (size_t)(j * 128 + 16 * wv + n16) * H_ + kc * 32 + quad * 8);

  f16x8 wih[4][4];
  if (layer) {
#pragma unroll
    for (int j = 0; j < 4; ++j)
#pragma unroll
      for (int kc = 0; kc < 4; ++kc)
        wih[j][kc] = load_w8(Wih + (size_t)(j * 128 + 16 * wv + n16) * H_ + kc * 32 + quad * 8);
  }
  f16x8 wx[4];
#pragma unroll
  for (int j = 0; j < 4; ++j)
#pragma unroll
    for (int i = 0; i < 8; ++i) wx[j][i] = (_Float16)0.f;
  if (!layer && quad == 0) {
#pragma unroll
    for (int j = 0; j < 4; ++j) {
      const float* p = Wih + (size_t)(j * 128 + 16 * wv + n16) * IN_;
#pragma unroll
      for (int i = 0; i < IN_; ++i) wx[j][i] = (_Float16)p[i];
    }
  }

  float bias[4][4];
#pragma unroll
  for (int j = 0; j < 4; ++j)
#pragma unroll
    for (int r = 0; r < 4; ++r) {
      int row = j * 128 + 16 * wv + quad * 4 + r;
      bias[j][r] = bih[row] + bhh[row];
    }

  f32x4 c4 = {0.f, 0.f, 0.f, 0.f};
  const f32x4 z4 = {0.f, 0.f, 0.f, 0.f};

  for (int i = tid; i < 2176; i += 512) ((unsigned int*)hstate)[i] = 0u;

  unsigned int* flag_in  = (layer > 0) ? &flags[(layer - 1) * 8 + bg] : nullptr;
  unsigned int* flag_out = (layer < 2) ? &flags[layer * 8 + bg] : nullptr;

  uint4 sreg[4];
  uint4 xreg = {0u, 0u, 0u, 0u};
  const int sn_h = tid >> 5, st_h = (tid >> 2) & 7, sq_h = tid & 3;  // h staging map
  const int sn_x = tid >> 3, st_x = tid & 7;                        // x staging map

  int have = 0;
  // ---- pre-stage group 0
  if (layer) {
    if (tid == 0)
      while (__hip_atomic_load(flag_in, __ATOMIC_ACQUIRE, __HIP_MEMORY_SCOPE_AGENT) < 1u)
        __builtin_amdgcn_s_sleep(8);
    have = 1;
  }
  __syncthreads();
  if (layer) {
    const uint4* gp = (const uint4*)(region + ((size_t)(bg * 16 + sn_h) * T_ + st_h) * H_ + sq_h * 32);
#pragma unroll
    for (int i = 0; i < 4; ++i) sreg[i] = gp[i];
    uint4* lp = (uint4*)&hbufL[st_h][sn_h][sq_h * 32];
#pragma unroll
    for (int i = 0; i < 4; ++i) lp[i] = sreg[i];
  } else if (tid < 128) {
    const float* xp = x + ((size_t)(bg * 16 + sn_x) * T_ + st_x) * IN_;
    xreg.x = pack2(xp[0], xp[1]); xreg.y = pack2(xp[2], xp[3]);
    xreg.z = pack2(xp[4], xp[5]); xreg.w = 0u;
    *(uint4*)&xbuf[st_x][sn_x][0] = xreg;
  }
  __syncthreads();

  unsigned int d0[GRP_], d1[GRP_];

  for (int g = 0; g < NGRP_; ++g) {
    int gs = (g + 1 < NGRP_) ? (g + 1) : g;

    // consumer: wait for producer chunk covering group gs
    if (layer) {
      int need = (8 * gs + 7) / CHUNK_ + 1;
      if (need > have) {
        if (tid == 0)
          while ((int)__hip_atomic_load(flag_in, __ATOMIC_ACQUIRE, __HIP_MEMORY_SCOPE_AGENT) < need)
            __builtin_amdgcn_s_sleep(8);
        __syncthreads();
        have = need;
      }
    }
    // issue next group's staging loads (consumed at group end)
    if (layer) {
      const uint4* gp = (const uint4*)(region + ((size_t)(bg * 16 + sn_h) * T_ + (8 * gs + st_h)) * H_ + sq_h * 32);
#pragma unroll
      for (int i = 0; i < 4; ++i) sreg[i] = gp[i];
    } else if (tid < 128) {
      const float* xp = x + ((size_t)(bg * 16 + sn_x) * T_ + (8 * gs + st_x)) * IN_;
      xreg.x = pack2(xp[0], xp[1]); xreg.y = pack2(xp[2], xp[3]);
      xreg.z = pack2(xp[4], xp[5]); xreg.w = 0u;
    }

    // ---- 8 recurrence steps
#pragma unroll
    for (int s = 0; s < GRP_; ++s) {
      const int rp = s & 1, wp = rp ^ 1;
      const int ko = quad * 8;

      f16x8 hs[4];
#pragma unroll
      for (int kc = 0; kc < 4; ++kc)
        hs[kc] = *(const f16x8*)&hstate[rp][n16][kc * 32 + ko];

      f32x4 acc[4];
      if (layer) {
        f16x8 hi[4];
#pragma unroll
        for (int kc = 0; kc < 4; ++kc)
          hi[kc] = *(const f16x8*)&hbufL[s][n16][kc * 32 + ko];
#pragma unroll
        for (int j = 0; j < 4; ++j) {
          f32x4 a = z4;
#pragma unroll
          for (int kc = 0; kc < 4; ++kc)
            a = __builtin_amdgcn_mfma_f32_16x16x32_f16(whh[j][kc], hs[kc], a, 0, 0, 0);
#pragma unroll
          for (int kc = 0; kc < 4; ++kc)
            a = __builtin_amdgcn_mfma_f32_16x16x32_f16(wih[j][kc], hi[kc], a, 0, 0, 0);
          acc[j] = a;
        }
      } else {
        f16x8 xi;
#pragma unroll
        for (int i = 0; i < 8; ++i) xi[i] = (_Float16)0.f;
        if (quad == 0) xi = *(const f16x8*)&xbuf[s][n16][0];
#pragma unroll
        for (int j = 0; j < 4; ++j) {
          f32x4 a = z4;
#pragma unroll
          for (int kc = 0; kc < 4; ++kc)
            a = __builtin_amdgcn_mfma_f32_16x16x32_f16(whh[j][kc], hs[kc], a, 0, 0, 0);
          a = __builtin_amdgcn_mfma_f32_16x16x32_f16(wx[j], xi, a, 0, 0, 0);
          acc[j] = a;
        }
      }

      float hv4[4];
#pragma unroll
      for (int r = 0; r < 4; ++r) {
        float i_ = sigf_(acc[0][r] + bias[0][r]);
        float f_ = sigf_(acc[1][r] + bias[1][r]);
        float g_ = tanhf_(acc[2][r] + bias[2][r]);
        float o_ = sigf_(acc[3][r] + bias[3][r]);
        float cc = f_ * c4[r] + i_ * g_;
        c4[r] = cc;
        hv4[r] = o_ * tanhf_(cc);
      }
      unsigned int u0 = pack2(hv4[0], hv4[1]);
      unsigned int u1 = pack2(hv4[2], hv4[3]);
      d0[s] = u0; d1[s] = u1;
      uint2 hw; hw.x = u0; hw.y = u1;
      *(uint2*)&hstate[wp][n16][16 * wv + quad * 4] = hw;
      __syncthreads();
    }

    // deferred h-sequence stores (producers only)
    if (layer < 2) {
#pragma unroll
      for (int s = 0; s < GRP_; ++s) {
        size_t off = ((size_t)(bg * 16 + n16) * T_ + (8 * g + s)) * H_ + 16 * wv + quad * 4;
        uint2 hw; hw.x = d0[s]; hw.y = d1[s];
        *(uint2*)(region + off) = hw;
      }
    }
    // staged regs -> LDS for next group
    if (layer) {
      uint4* lp = (uint4*)&hbufL[st_h][sn_h][sq_h * 32];
#pragma unroll
      for (int i = 0; i < 4; ++i) lp[i] = sreg[i];
    } else if (tid < 128) {
      *(uint4*)&xbuf[st_x][sn_x][0] = xreg;
    }
    __syncthreads();  // drains stores (vmcnt) + publishes LDS

    // producer: commit chunk
    if (layer < 2 && ((8 * g + 8) % CHUNK_) == 0 && tid == 0) {
      __threadfence();
      __hip_atomic_store(flag_out, (unsigned int)((8 * g + 8) / CHUNK_),
                         __ATOMIC_RELEASE, __HIP_MEMORY_SCOPE_AGENT);
    }
  }

  if (layer == 2) {
    state_h[(bg * 16 + n16) * 64 + 8 * wv + 2 * quad]     = d0[GRP_ - 1];
    state_h[(bg * 16 + n16) * 64 + 8 * wv + 2 * quad + 1] = d1[GRP_ - 1];
  }
}

// ---------------------------------------------------------------------------
// Head: out[b] = h_last[b,:] . W_out + b_out   (fp32 out)
// ---------------------------------------------------------------------------
__global__ void head_kernel(const unsigned int* __restrict__ state_h,  // [B][64] f16x2
                            const float* __restrict__ Wout,            // fp32 [128]
                            const float* __restrict__ bout,            // fp32 [1]
                            float* __restrict__ out)                   // fp32 [128]
{
  int b = threadIdx.x;  // 128 threads, 1 block
  float s = bout[0];
  for (int j = 0; j < 64; ++j) {
    unsigned int p = state_h[b * 64 + j];
    union { unsigned short u; _Float16 h; } lo, hi;
    lo.u = (unsigned short)(p & 0xffffu);
    hi.u = (unsigned short)(p >> 16);
    s += (float)lo.h * Wout[2 * j] + (float)hi.h * Wout[2 * j + 1];
  }
  out[b] = s;
}

// ---------------------------------------------------------------------------
extern "C" void kernel_launch(void* const* d_in, const int* in_sizes, int n_in,
                              void* d_out, int out_size, void* d_ws, size_t ws_size,
                              hipStream_t stream)
{
  const float* x = (const float*)d_in[0];
  const float* Wih[3] = {(const float*)d_in[1], (const float*)d_in[5], (const float*)d_in[9]};
  const float* Whh[3] = {(const float*)d_in[2], (const float*)d_in[6], (const float*)d_in[10]};
  const float* bih[3] = {(const float*)d_in[3], (const float*)d_in[7], (const float*)d_in[11]};
  const float* bhh[3] = {(const float*)d_in[4], (const float*)d_in[8], (const float*)d_in[12]};
  const float* Wout = (const float*)d_in[13];
  const float* bout = (const float*)d_in[14];
  float* out = (float*)d_out;

  char* ws = (char*)d_ws;
  size_t off = 0;
  unsigned short* region = (unsigned short*)(ws + off); off += (size_t)B_ * T_ * H_ * 2;  // 64 MiB
  unsigned int* state_h  = (unsigned int*)(ws + off);   off += (size_t)B_ * 64 * 4;
  unsigned int* flags    = (unsigned int*)(ws + off);   off += 16 * 4;

  init_flags<<<1, 64, 0, stream>>>(flags);
  lstm_pipe<<<24, 512, 0, stream>>>(x,
      Wih[0], Whh[0], bih[0], bhh[0],
      Wih[1], Whh[1], bih[1], bhh[1],
      Wih[2], Whh[2], bih[2], bhh[2],
      region, state_h, flags);
  head_kernel<<<1, 128, 0, stream>>>(state_h, Wout, bout, out);
}

// Round 6
// 4561.955 us; speedup vs baseline: 1.3231x; 1.0327x over previous
//
#include <hip/hip_runtime.h>

#define B_ 128
#define T_ 2048
#define H_ 128
#define IN_ 6
#define GRP_ 8            // steps per inner group
#define NGRP_ (T_ / GRP_) // 256
#define FLAG_STRIDE_ 64   // uints between flags (256B, no false sharing)

typedef _Float16 f16x8 __attribute__((ext_vector_type(8)));
typedef float    f32x4 __attribute__((ext_vector_type(4)));

__device__ __forceinline__ unsigned short f2h_u(float f) {
  union { _Float16 h; unsigned short u; } v; v.h = (_Float16)f; return v.u;
}
__device__ __forceinline__ unsigned int pack2(float a, float b) {
  return (unsigned int)f2h_u(a) | ((unsigned int)f2h_u(b) << 16);
}
__device__ __forceinline__ float sigf_(float x) { return 1.0f / (1.0f + __expf(-x)); }
__device__ __forceinline__ float tanhf_(float x) {
  x = fminf(fmaxf(x, -15.f), 15.f);
  float e = __expf(2.f * x);
  return (e - 1.f) / (e + 1.f);
}
__device__ __forceinline__ f16x8 load_w8(const float* __restrict__ p) {
  f16x8 r;
#pragma unroll
  for (int i = 0; i < 8; ++i) r[i] = (_Float16)p[i];
  return r;
}

__global__ void init_flags(unsigned int* flags) {
  flags[blockIdx.x * 256 + threadIdx.x] = 0u;
}

// ---------------------------------------------------------------------------
// Persistent pipelined 3-layer LSTM. 24 WGs: layer = bid>>3, batch-group = bid&7.
// Handoff: region f16 [B][T][128] (in-place), per-group release/acquire flags.
// Consumer polls with RELAXED loads (no cache-maintenance) + one ACQUIRE.
// ---------------------------------------------------------------------------
__global__ __launch_bounds__(512, 2)
void lstm_pipe(const float* __restrict__ x,
               const float* __restrict__ Wih0, const float* __restrict__ Whh0,
               const float* __restrict__ bih0, const float* __restrict__ bhh0,
               const float* __restrict__ Wih1, const float* __restrict__ Whh1,
               const float* __restrict__ bih1, const float* __restrict__ bhh1,
               const float* __restrict__ Wih2, const float* __restrict__ Whh2,
               const float* __restrict__ bih2, const float* __restrict__ bhh2,
               unsigned short* __restrict__ region,
               unsigned int* __restrict__ state_h,
               unsigned int* __restrict__ flags)
{
  const int layer = blockIdx.x >> 3;
  const int bg    = blockIdx.x & 7;
  const int tid   = threadIdx.x;
  const int lane  = tid & 63;
  const int wv    = tid >> 6;       // 0..7: owns units [16wv,16wv+16)
  const int n16   = lane & 15;      // batch within group
  const int quad  = lane >> 4;

  const float* Wih = (layer == 0) ? Wih0 : ((layer == 1) ? Wih1 : Wih2);
  const float* Whh = (layer == 0) ? Whh0 : ((layer == 1) ? Whh1 : Whh2);
  const float* bih = (layer == 0) ? bih0 : ((layer == 1) ? bih1 : bih2);
  const float* bhh = (layer == 0) ? bhh0 : ((layer == 1) ? bhh1 : bhh2);

  __shared__ unsigned short hstate[2][16][136];
  __shared__ unsigned short hbufL[GRP_][16][136];
  __shared__ unsigned short xbuf[GRP_][16][8];
  __shared__ int s_have;

  // ---- weights -> register A-frags
  f16x8 whh[4][4];
#pragma unroll
  for (int j = 0; j < 4; ++j)
#pragma unroll
    for (int kc = 0; kc < 4; ++kc)
      whh[j][kc] = load_w8(Whh + (size_t)(j * 128 + 16 * wv + n16) * H_ + kc * 32 + quad * 8);

  f16x8 wih[4][4];
  if (layer) {
#pragma unroll
    for (int j = 0; j < 4; ++j)
#pragma unroll
      for (int kc = 0; kc < 4; ++kc)
        wih[j][kc] = load_w8(Wih + (size_t)(j * 128 + 16 * wv + n16) * H_ + kc * 32 + quad * 8);
  }
  f16x8 wx[4];
#pragma unroll
  for (int j = 0; j < 4; ++j)
#pragma unroll
    for (int i = 0; i < 8; ++i) wx[j][i] = (_Float16)0.f;
  if (!layer && quad == 0) {
#pragma unroll
    for (int j = 0; j < 4; ++j) {
      const float* p = Wih + (size_t)(j * 128 + 16 * wv + n16) * IN_;
#pragma unroll
      for (int i = 0; i < IN_; ++i) wx[j][i] = (_Float16)p[i];
    }
  }

  // bias folded into MFMA C-init
  f32x4 bias4[4];
#pragma unroll
  for (int j = 0; j < 4; ++j)
#pragma unroll
    for (int r = 0; r < 4; ++r) {
      int row = j * 128 + 16 * wv + quad * 4 + r;
      bias4[j][r] = bih[row] + bhh[row];
    }

  f32x4 c4 = {0.f, 0.f, 0.f, 0.f};

  for (int i = tid; i < 2176; i += 512) ((unsigned int*)hstate)[i] = 0u;

  unsigned int* flag_in  = (layer > 0) ? &flags[((layer - 1) * 8 + bg) * FLAG_STRIDE_] : nullptr;
  unsigned int* flag_out = (layer < 2) ? &flags[(layer * 8 + bg) * FLAG_STRIDE_] : nullptr;

  uint4 sreg[4];
  uint4 xreg = {0u, 0u, 0u, 0u};
  const int sn_h = tid >> 5, st_h = (tid >> 2) & 7, sq_h = tid & 3;
  const int sn_x = tid >> 3, st_x = tid & 7;

  int have = 0;

  // ---- consumer wait helper (inlined twice): relaxed poll, acquire finalize
#define WAIT_FOR(need_)                                                          \
  do {                                                                           \
    if (have < (need_)) {                                                        \
      if (tid == 0) {                                                            \
        int v = (int)__hip_atomic_load(flag_in, __ATOMIC_RELAXED,                \
                                       __HIP_MEMORY_SCOPE_AGENT);                \
        int spins = 0;                                                           \
        while (v < (need_)) {                                                    \
          __builtin_amdgcn_s_sleep(8);                                           \
          ++spins;                                                               \
          v = (spins < 200000)                                                   \
            ? (int)__hip_atomic_load(flag_in, __ATOMIC_RELAXED,                  \
                                     __HIP_MEMORY_SCOPE_AGENT)                   \
            : (int)__hip_atomic_load(flag_in, __ATOMIC_ACQUIRE,                  \
                                     __HIP_MEMORY_SCOPE_AGENT);                  \
        }                                                                        \
        (void)__hip_atomic_load(flag_in, __ATOMIC_ACQUIRE,                       \
                                __HIP_MEMORY_SCOPE_AGENT);                       \
        s_have = v;                                                              \
      }                                                                          \
      __syncthreads();                                                           \
      have = s_have;                                                             \
    }                                                                            \
  } while (0)

  // ---- pre-stage group 0
  if (layer) WAIT_FOR(1);
  __syncthreads();
  if (layer) {
    const uint4* gp = (const uint4*)(region + ((size_t)(bg * 16 + sn_h) * T_ + st_h) * H_ + sq_h * 32);
#pragma unroll
    for (int i = 0; i < 4; ++i) sreg[i] = gp[i];
    uint4* lp = (uint4*)&hbufL[st_h][sn_h][sq_h * 32];
#pragma unroll
    for (int i = 0; i < 4; ++i) lp[i] = sreg[i];
  } else if (tid < 128) {
    const float* xp = x + ((size_t)(bg * 16 + sn_x) * T_ + st_x) * IN_;
    xreg.x = pack2(xp[0], xp[1]); xreg.y = pack2(xp[2], xp[3]);
    xreg.z = pack2(xp[4], xp[5]); xreg.w = 0u;
    *(uint4*)&xbuf[st_x][sn_x][0] = xreg;
  }
  __syncthreads();

  unsigned int d0[GRP_], d1[GRP_];

  for (int g = 0; g < NGRP_; ++g) {
    int gs = (g + 1 < NGRP_) ? (g + 1) : g;

    // consumer: need producer groups-completed >= gs+1 (covers steps 8gs..8gs+7)
    if (layer) WAIT_FOR(gs + 1);

    // issue next group's staging loads (consumed at group end)
    if (layer) {
      const uint4* gp = (const uint4*)(region + ((size_t)(bg * 16 + sn_h) * T_ + (8 * gs + st_h)) * H_ + sq_h * 32);
#pragma unroll
      for (int i = 0; i < 4; ++i) sreg[i] = gp[i];
    } else if (tid < 128) {
      const float* xp = x + ((size_t)(bg * 16 + sn_x) * T_ + (8 * gs + st_x)) * IN_;
      xreg.x = pack2(xp[0], xp[1]); xreg.y = pack2(xp[2], xp[3]);
      xreg.z = pack2(xp[4], xp[5]); xreg.w = 0u;
    }

    // ---- 8 recurrence steps
#pragma unroll
    for (int s = 0; s < GRP_; ++s) {
      const int rp = s & 1, wp = rp ^ 1;
      const int ko = quad * 8;

      f16x8 hs[4];
#pragma unroll
      for (int kc = 0; kc < 4; ++kc)
        hs[kc] = *(const f16x8*)&hstate[rp][n16][kc * 32 + ko];

      f32x4 acc[4];
      if (layer) {
        f16x8 hi[4];
#pragma unroll
        for (int kc = 0; kc < 4; ++kc)
          hi[kc] = *(const f16x8*)&hbufL[s][n16][kc * 32 + ko];
#pragma unroll
        for (int j = 0; j < 4; ++j) {
          f32x4 a = bias4[j];
#pragma unroll
          for (int kc = 0; kc < 4; ++kc)
            a = __builtin_amdgcn_mfma_f32_16x16x32_f16(whh[j][kc], hs[kc], a, 0, 0, 0);
#pragma unroll
          for (int kc = 0; kc < 4; ++kc)
            a = __builtin_amdgcn_mfma_f32_16x16x32_f16(wih[j][kc], hi[kc], a, 0, 0, 0);
          acc[j] = a;
        }
      } else {
        f16x8 xi;
#pragma unroll
        for (int i = 0; i < 8; ++i) xi[i] = (_Float16)0.f;
        if (quad == 0) xi = *(const f16x8*)&xbuf[s][n16][0];
#pragma unroll
        for (int j = 0; j < 4; ++j) {
          f32x4 a = bias4[j];
#pragma unroll
          for (int kc = 0; kc < 4; ++kc)
            a = __builtin_amdgcn_mfma_f32_16x16x32_f16(whh[j][kc], hs[kc], a, 0, 0, 0);
          a = __builtin_amdgcn_mfma_f32_16x16x32_f16(wx[j], xi, a, 0, 0, 0);
          acc[j] = a;
        }
      }

      float hv4[4];
#pragma unroll
      for (int r = 0; r < 4; ++r) {
        float i_ = sigf_(acc[0][r]);
        float f_ = sigf_(acc[1][r]);
        float g_ = tanhf_(acc[2][r]);
        float o_ = sigf_(acc[3][r]);
        float cc = f_ * c4[r] + i_ * g_;
        c4[r] = cc;
        hv4[r] = o_ * tanhf_(cc);
      }
      unsigned int u0 = pack2(hv4[0], hv4[1]);
      unsigned int u1 = pack2(hv4[2], hv4[3]);
      d0[s] = u0; d1[s] = u1;
      uint2 hw; hw.x = u0; hw.y = u1;
      *(uint2*)&hstate[wp][n16][16 * wv + quad * 4] = hw;
      __syncthreads();
    }

    // deferred h-sequence stores (producers only)
    if (layer < 2) {
#pragma unroll
      for (int s = 0; s < GRP_; ++s) {
        size_t off = ((size_t)(bg * 16 + n16) * T_ + (8 * g + s)) * H_ + 16 * wv + quad * 4;
        uint2 hw; hw.x = d0[s]; hw.y = d1[s];
        *(uint2*)(region + off) = hw;
      }
    }
    // staged regs -> LDS for next group
    if (layer) {
      uint4* lp = (uint4*)&hbufL[st_h][sn_h][sq_h * 32];
#pragma unroll
      for (int i = 0; i < 4; ++i) lp[i] = sreg[i];
    } else if (tid < 128) {
      *(uint4*)&xbuf[st_x][sn_x][0] = xreg;
    }
    __syncthreads();  // drains region stores (vmcnt) + publishes LDS

    // producer: publish every group (release orders the region stores)
    if (layer < 2 && tid == 0) {
      __hip_atomic_store(flag_out, (unsigned int)(g + 1),
                         __ATOMIC_RELEASE, __HIP_MEMORY_SCOPE_AGENT);
    }
  }
#undef WAIT_FOR

  if (layer == 2) {
    state_h[(bg * 16 + n16) * 64 + 8 * wv + 2 * quad]     = d0[GRP_ - 1];
    state_h[(bg * 16 + n16) * 64 + 8 * wv + 2 * quad + 1] = d1[GRP_ - 1];
  }
}

// ---------------------------------------------------------------------------
__global__ void head_kernel(const unsigned int* __restrict__ state_h,
                            const float* __restrict__ Wout,
                            const float* __restrict__ bout,
                            float* __restrict__ out)
{
  int b = threadIdx.x;  // 128 threads, 1 block
  float s = bout[0];
  for (int j = 0; j < 64; ++j) {
    unsigned int p = state_h[b * 64 + j];
    union { unsigned short u; _Float16 h; } lo, hi;
    lo.u = (unsigned short)(p & 0xffffu);
    hi.u = (unsigned short)(p >> 16);
    s += (float)lo.h * Wout[2 * j] + (float)hi.h * Wout[2 * j + 1];
  }
  out[b] = s;
}

// ---------------------------------------------------------------------------
extern "C" void kernel_launch(void* const* d_in, const int* in_sizes, int n_in,
                              void* d_out, int out_size, void* d_ws, size_t ws_size,
                              hipStream_t stream)
{
  const float* x = (const float*)d_in[0];
  const float* Wih[3] = {(const float*)d_in[1], (const float*)d_in[5], (const float*)d_in[9]};
  const float* Whh[3] = {(const float*)d_in[2], (const float*)d_in[6], (const float*)d_in[10]};
  const float* bih[3] = {(const float*)d_in[3], (const float*)d_in[7], (const float*)d_in[11]};
  const float* bhh[3] = {(const float*)d_in[4], (const float*)d_in[8], (const float*)d_in[12]};
  const float* Wout = (const float*)d_in[13];
  const float* bout = (const float*)d_in[14];
  float* out = (float*)d_out;

  char* ws = (char*)d_ws;
  size_t off = 0;
  unsigned short* region = (unsigned short*)(ws + off); off += (size_t)B_ * T_ * H_ * 2;  // 64 MiB
  unsigned int* state_h  = (unsigned int*)(ws + off);   off += (size_t)B_ * 64 * 4;
  off = (off + 255) & ~(size_t)255;
  unsigned int* flags    = (unsigned int*)(ws + off);   off += 16 * FLAG_STRIDE_ * 4;

  init_flags<<<4, 256, 0, stream>>>(flags);
  lstm_pipe<<<24, 512, 0, stream>>>(x,
      Wih[0], Whh[0], bih[0], bhh[0],
      Wih[1], Whh[1], bih[1], bhh[1],
      Wih[2], Whh[2], bih[2], bhh[2],
      region, state_h, flags);
  head_kernel<<<1, 128, 0, stream>>>(state_h, Wout, bout, out);
}